// Round 4
// baseline (407.246 us; speedup 1.0000x reference)
//
#include <hip/hip_runtime.h>
#include <cstdint>
#include <cstddef>

// Problem constants: B=64, N=1024, D=512, C=512, K=16, GAMMA=0.3, TEMP=0.07
#define INV_TEMP 14.285714285714285714f
#define GAMMA_ 0.3f

// A-matrix row layout: rows 0..65535 = patches (b*1024+n); rows 65536..65599
// = cls per b; rows 65600..65663 = zero padding (tile 512 of 513).
// Pack kernel also handles B rows 65664..66175 -> text 0..511.
#define ROWS_PAD 65664

typedef short short8 __attribute__((ext_vector_type(8)));
typedef float floatx4 __attribute__((ext_vector_type(4)));

#if __has_builtin(__builtin_amdgcn_fmed3f)
#define MED3(v, hi, lo) __builtin_amdgcn_fmed3f((v), (hi), (lo))
#else
#define MED3(v, hi, lo) fmaxf(fminf((v), (hi)), (lo))
#endif

__device__ __forceinline__ unsigned short f2bf(float x) {
  unsigned int u = __float_as_uint(x);
  u += 0x7FFFu + ((u >> 16) & 1u);  // round-to-nearest-even
  return (unsigned short)(u >> 16);
}
__device__ __forceinline__ float bf2f(unsigned short h) {
  return __uint_as_float(((unsigned int)h) << 16);
}

// Branchless sorted-descending top-16 insert: 15 med3 + 1 max, depth-1 ILP.
__device__ __forceinline__ void insert16(float (&top)[16], float v) {
#pragma unroll
  for (int j = 15; j >= 1; --j) top[j] = MED3(v, top[j - 1], top[j]);
  top[0] = fmaxf(top[0], v);
}

// ---------------------------------------------------------------------------
// Unified pack: one wave per row, l2-normalize + bf16 hi/lo split.
// wave id: [0,65536) patches; [65536,65600) cls; [65600,65664) zero-pad;
// [65664,66176) text rows -> Bh/Bl. Wave-uniform branches only.
__global__ __launch_bounds__(256) void pack_all_kernel(
    const float* __restrict__ vpat, const float* __restrict__ vcls,
    const float* __restrict__ text, unsigned short* __restrict__ Ahi,
    unsigned short* __restrict__ Alo, unsigned short* __restrict__ Bh,
    unsigned short* __restrict__ Bl) {
  const int wid = blockIdx.x * 4 + (threadIdx.x >> 6);
  const int lane = threadIdx.x & 63;
  const float* src;
  unsigned short *hi, *lo;
  size_t orow;
  if (wid < 65536) {
    src = vpat + (size_t)wid * 512; hi = Ahi; lo = Alo; orow = wid;
  } else if (wid < 65600) {
    src = vcls + (size_t)(wid - 65536) * 512; hi = Ahi; lo = Alo; orow = wid;
  } else if (wid < 65664) {
    const ushort4 z = {0, 0, 0, 0};
    ((ushort4*)(Ahi + (size_t)wid * 512))[lane] = z;
    ((ushort4*)(Ahi + (size_t)wid * 512))[lane + 64] = z;
    ((ushort4*)(Alo + (size_t)wid * 512))[lane] = z;
    ((ushort4*)(Alo + (size_t)wid * 512))[lane + 64] = z;
    return;
  } else {
    src = text + (size_t)(wid - 65664) * 512; hi = Bh; lo = Bl;
    orow = wid - 65664;
  }
  const float4 v0 = ((const float4*)src)[lane];
  const float4 v1 = ((const float4*)src)[lane + 64];
  float ss = v0.x * v0.x + v0.y * v0.y + v0.z * v0.z + v0.w * v0.w +
             v1.x * v1.x + v1.y * v1.y + v1.z * v1.z + v1.w * v1.w;
#pragma unroll
  for (int off = 32; off; off >>= 1) ss += __shfl_xor(ss, off);
  const float scale = 1.0f / fmaxf(sqrtf(ss), 1e-12f);
  float a[8] = {v0.x * scale, v0.y * scale, v0.z * scale, v0.w * scale,
                v1.x * scale, v1.y * scale, v1.z * scale, v1.w * scale};
  ushort4 h0, l0, h1, l1;
  h0.x = f2bf(a[0]); l0.x = f2bf(a[0] - bf2f(h0.x));
  h0.y = f2bf(a[1]); l0.y = f2bf(a[1] - bf2f(h0.y));
  h0.z = f2bf(a[2]); l0.z = f2bf(a[2] - bf2f(h0.z));
  h0.w = f2bf(a[3]); l0.w = f2bf(a[3] - bf2f(h0.w));
  h1.x = f2bf(a[4]); l1.x = f2bf(a[4] - bf2f(h1.x));
  h1.y = f2bf(a[5]); l1.y = f2bf(a[5] - bf2f(h1.y));
  h1.z = f2bf(a[6]); l1.z = f2bf(a[6] - bf2f(h1.z));
  h1.w = f2bf(a[7]); l1.w = f2bf(a[7] - bf2f(h1.w));
  ((ushort4*)(hi + orow * 512))[lane] = h0;
  ((ushort4*)(hi + orow * 512))[lane + 64] = h1;
  ((ushort4*)(lo + orow * 512))[lane] = l0;
  ((ushort4*)(lo + orow * 512))[lane + 64] = l1;
}

// ---------------------------------------------------------------------------
// Split-bf16 3-term MFMA GEMM + slim fused softmax partial sum + coalesced
// LDS-transpose epilogue (full-line dwordx4 stores -> no write-allocate RMW).
// logits[m][c] = A[m][:] . B[c][:], K=512. Block 256 thr (2x2 waves),
// tile 128x128, BK=32, 16x16x32 bf16 MFMA, XOR-swizzled 16B-chunk LDS.
// |logit| <= 1 (l2-normalized rows) -> fixed softmax max 1.0, no max-reduce.
__global__ __launch_bounds__(256) void gemm_split_kernel(
    const unsigned short* __restrict__ Ahi, const unsigned short* __restrict__ Alo,
    const unsigned short* __restrict__ Bhi, const unsigned short* __restrict__ Blo,
    float* __restrict__ Cout, float* __restrict__ pstat) {
  __shared__ __align__(16) unsigned short smem[16384];  // 32 KB
  unsigned short* sAh = smem;
  unsigned short* sAl = smem + 4096;
  unsigned short* sBh = smem + 8192;
  unsigned short* sBl = smem + 12288;
  const int tid = threadIdx.x;
  const int lane = tid & 63;
  const int w = tid >> 6;
  const int wm = w >> 1, wn = w & 1;
  const int bn = blockIdx.x, bm = blockIdx.y;

  const int i0 = tid, i1 = 256 + tid;
  const int m0 = i0 >> 2, g0 = (i0 & 3) ^ ((m0 >> 1) & 3);
  const int m1 = i1 >> 2, g1 = (i1 & 3) ^ ((m1 >> 1) & 3);
  const unsigned aO0 = (unsigned)(bm * 128 + m0) * 512u + (unsigned)g0 * 8u;
  const unsigned aO1 = (unsigned)(bm * 128 + m1) * 512u + (unsigned)g1 * 8u;
  const unsigned bO0 = (unsigned)(bn * 128 + m0) * 512u + (unsigned)g0 * 8u;
  const unsigned bO1 = (unsigned)(bn * 128 + m1) * 512u + (unsigned)g1 * 8u;
  const unsigned ldsQ0 = (unsigned)(w * 64) * 8u;
  const unsigned ldsQ1 = (unsigned)(256 + w * 64) * 8u;

  const int l15 = lane & 15, kg = lane >> 4;
  int cA[4], cB[4];
#pragma unroll
  for (int i = 0; i < 4; ++i) {
    const int ml = wm * 64 + i * 16 + l15;
    cA[i] = (ml * 4 + (kg ^ ((ml >> 1) & 3))) * 8;
    const int nl = wn * 64 + i * 16 + l15;
    cB[i] = (nl * 4 + (kg ^ ((nl >> 1) & 3))) * 8;
  }

  floatx4 acc[4][4] = {};

#define GL16(srcp, dstp)                                                        \
  __builtin_amdgcn_global_load_lds(                                             \
      (const __attribute__((address_space(1))) void*)(srcp),                    \
      (__attribute__((address_space(3))) void*)(dstp), 16, 0, 0)

  for (int ks = 0; ks < 16; ++ks) {
    const unsigned ko = (unsigned)ks * 32u;
    GL16(Ahi + aO0 + ko, sAh + ldsQ0);
    GL16(Ahi + aO1 + ko, sAh + ldsQ1);
    GL16(Alo + aO0 + ko, sAl + ldsQ0);
    GL16(Alo + aO1 + ko, sAl + ldsQ1);
    GL16(Bhi + bO0 + ko, sBh + ldsQ0);
    GL16(Bhi + bO1 + ko, sBh + ldsQ1);
    GL16(Blo + bO0 + ko, sBl + ldsQ0);
    GL16(Blo + bO1 + ko, sBl + ldsQ1);
    __syncthreads();

    short8 ah[4], al[4], bh[4], bl[4];
#pragma unroll
    for (int i = 0; i < 4; ++i) {
      ah[i] = *(const short8*)(sAh + cA[i]);
      al[i] = *(const short8*)(sAl + cA[i]);
      bh[i] = *(const short8*)(sBh + cB[i]);
      bl[i] = *(const short8*)(sBl + cB[i]);
    }
#pragma unroll
    for (int i = 0; i < 4; ++i) {
#pragma unroll
      for (int j = 0; j < 4; ++j) {
        acc[i][j] = __builtin_amdgcn_mfma_f32_16x16x32_bf16(ah[i], bh[j], acc[i][j], 0, 0, 0);
        acc[i][j] = __builtin_amdgcn_mfma_f32_16x16x32_bf16(ah[i], bl[j], acc[i][j], 0, 0, 0);
        acc[i][j] = __builtin_amdgcn_mfma_f32_16x16x32_bf16(al[i], bh[j], acc[i][j], 0, 0, 0);
      }
    }
    __syncthreads();
  }
#undef GL16

  // C/D layout: col=lane&15, row=(lane>>4)*4+reg  [m89/m91 verified]
  const int quad = lane >> 4;
  const unsigned rowb0 = (unsigned)(bm * 128 + wm * 64 + quad * 4);

  // Slim fused partial sumexp (fixed max=1.0): 16-lane quad shfl-sum only.
  const int pk = bn * 2 + wn;  // slot 0..7
#pragma unroll
  for (int i = 0; i < 4; ++i) {
#pragma unroll
    for (int r = 0; r < 4; ++r) {
      float se = __expf((acc[i][0][r] - 1.0f) * INV_TEMP) +
                 __expf((acc[i][1][r] - 1.0f) * INV_TEMP) +
                 __expf((acc[i][2][r] - 1.0f) * INV_TEMP) +
                 __expf((acc[i][3][r] - 1.0f) * INV_TEMP);
      se += __shfl_xor(se, 1);
      se += __shfl_xor(se, 2);
      se += __shfl_xor(se, 4);
      se += __shfl_xor(se, 8);
      if (l15 == 0) {
        const unsigned row = rowb0 + i * 16 + r;
        pstat[(size_t)row * 8 + pk] = se;
      }
    }
  }

  // Coalesced epilogue: two half-tiles (64 rows x 128 cols = 32 KB) through
  // LDS. Writers swizzle col bit4 by row-quad parity (2 lanes/bank = free);
  // readers emit full 128-B-line dwordx4 stores (512 B per 32 lanes).
  float* sep = (float*)smem;
  const int qpar = quad & 1;
#pragma unroll
  for (int half = 0; half < 2; ++half) {
    __syncthreads();
    if (wm == half) {
#pragma unroll
      for (int i = 0; i < 4; ++i) {
#pragma unroll
        for (int j = 0; j < 4; ++j) {
          const int col = wn * 64 + j * 16 + l15;
          const int colp = col ^ (qpar << 4);
#pragma unroll
          for (int r = 0; r < 4; ++r) {
            const int lr = i * 16 + quad * 4 + r;  // local row 0..63
            sep[lr * 128 + colp] = acc[i][j][r];
          }
        }
      }
    }
    __syncthreads();
    const unsigned growb = (unsigned)(bm * 128 + half * 64);
#pragma unroll
    for (int it = 0; it < 8; ++it) {
      const int row = it * 8 + (tid >> 5);       // 0..63
      const int col4 = (tid & 31) * 4;           // 0..124
      const int s = ((row >> 2) & 1) << 4;
      const float4 val = *(const float4*)&sep[row * 128 + (col4 ^ s)];
      *(float4*)&Cout[(size_t)(growb + row) * 512 + (unsigned)(bn * 128 + col4)] = val;
    }
  }
}

// ---------------------------------------------------------------------------
// LW[m] = -(ln(sum_pk pstat) + invT); aff[m][c] = exp(fma(l, invT, LW[m])).
__global__ __launch_bounds__(256) void lw_kernel(
    const float* __restrict__ pstat, float* __restrict__ LW) {
  const int m = blockIdx.x * 256 + threadIdx.x;
  const float* p = pstat + (size_t)m * 8;
  float S = 0.f;
#pragma unroll
  for (int k = 0; k < 8; ++k) S += p[k];
  LW[m] = -(__logf(S) + INV_TEMP);
}

// ---------------------------------------------------------------------------
// Partial top-16 per (b,c) over an n-chunk of 128, in s = l*invT + LW[n]
// domain (no exp in inner loop). Thread = one c; coalesced column reads.
__global__ __launch_bounds__(256) void topk_partial_kernel(
    const float* __restrict__ L, const float* __restrict__ LW,
    float* __restrict__ cand) {
  const int b = blockIdx.x;
  const int c = blockIdx.y * 256 + threadIdx.x;
  const int nc = blockIdx.z;
  float top[16];
#pragma unroll
  for (int t = 0; t < 16; ++t) top[t] = -3.0e38f;
  const size_t mb = (size_t)b * 1024 + (size_t)nc * 128;
  const float* Lp = L + mb * 512 + c;
  const float* Wp = LW + mb;
  for (int n0 = 0; n0 < 128; n0 += 8) {
    float s[8];
#pragma unroll
    for (int u = 0; u < 8; ++u)
      s[u] = fmaf(Lp[(size_t)(n0 + u) * 512], INV_TEMP, Wp[n0 + u]);
#pragma unroll
    for (int u = 0; u < 8; ++u) insert16(top, s[u]);
  }
  float* o = cand + ((size_t)b * 8 + nc) * 16 * 512 + c;
#pragma unroll
  for (int t = 0; t < 16; ++t) o[(size_t)t * 512] = top[t];
}

// Merge 8x16 s-candidates -> top-16 mean; fused aff_g from cls logit rows.
__global__ __launch_bounds__(256) void topk_merge_kernel(
    const float* __restrict__ cand, const float* __restrict__ logits,
    const float* __restrict__ LW, float* __restrict__ out) {
  const int gid = blockIdx.x * 256 + threadIdx.x;  // b*512 + c
  const int b = gid >> 9, c = gid & 511;
  const float* cb = cand + (size_t)b * 128 * 512 + c;
  float top[16];
#pragma unroll
  for (int t = 0; t < 16; ++t) top[t] = -3.0e38f;
  for (int kb = 0; kb < 8; ++kb) {
    float v[16];
#pragma unroll
    for (int j = 0; j < 16; ++j) v[j] = cb[(size_t)(kb * 16 + j) * 512];
#pragma unroll
    for (int j = 0; j < 16; ++j) insert16(top, v[j]);
  }
  float s = 0.f;
#pragma unroll
  for (int t = 0; t < 16; ++t) s += __expf(top[t]);
  const float lg = logits[((size_t)65536 + b) * 512 + c];
  const float ag = __expf(fmaf(lg, INV_TEMP, LW[65536 + b]));
  out[gid] = GAMMA_ * ag + (1.0f - GAMMA_) * (s * (1.0f / 16.0f));
}

// ---------------------------------------------------------------------------
extern "C" void kernel_launch(void* const* d_in, const int* in_sizes, int n_in,
                              void* d_out, int out_size, void* d_ws, size_t ws_size,
                              hipStream_t stream) {
  const float* vcls = (const float*)d_in[0];  // [64,512]
  const float* vpat = (const float*)d_in[1];  // [64,1024,512]
  const float* text = (const float*)d_in[2];  // [512,512]
  float* out = (float*)d_out;                 // [64,512]

  char* p = (char*)d_ws;
  auto carve = [&](size_t bytes) -> char* {
    char* r = p;
    p += (bytes + 255) & ~(size_t)255;
    return r;
  };
  unsigned short* Ahi = (unsigned short*)carve((size_t)ROWS_PAD * 512 * 2);
  unsigned short* Alo = (unsigned short*)carve((size_t)ROWS_PAD * 512 * 2);
  float* logits = (float*)carve((size_t)ROWS_PAD * 512 * 4);
  unsigned short* Bh = (unsigned short*)carve((size_t)512 * 512 * 2);
  unsigned short* Bl = (unsigned short*)carve((size_t)512 * 512 * 2);
  float* pstat = (float*)carve((size_t)65792 * 8 * 4);
  float* LW = (float*)carve((size_t)65792 * 4);
  // cand [64][8][16][512] f32 = 16.8 MB aliases Ahi (dead after gemm).
  float* cand = (float*)Ahi;
  if ((size_t)(p - (char*)d_ws) > ws_size) return;

  pack_all_kernel<<<16544, 256, 0, stream>>>(vpat, vcls, text, Ahi, Alo, Bh, Bl);
  gemm_split_kernel<<<dim3(4, 513), 256, 0, stream>>>(Ahi, Alo, Bh, Bl, logits, pstat);
  lw_kernel<<<257, 256, 0, stream>>>(pstat, LW);
  topk_partial_kernel<<<dim3(64, 2, 8), 256, 0, stream>>>(logits, LW, cand);
  topk_merge_kernel<<<128, 256, 0, stream>>>(cand, logits, LW, out);
}

// Round 5
// 385.235 us; speedup vs baseline: 1.0571x; 1.0571x over previous
//
#include <hip/hip_runtime.h>
#include <cstdint>
#include <cstddef>

// Problem constants: B=64, N=1024, D=512, C=512, K=16, GAMMA=0.3, TEMP=0.07
#define INV_TEMP 14.285714285714285714f
#define GAMMA_ 0.3f

// A-matrix row layout: rows 0..65535 = patches (b*1024+n); rows 65536..65599
// = cls per b; rows 65600..65663 = zero padding (tile 512 of 513).
// Pack kernel also handles B rows 65664..66175 -> text 0..511.
#define ROWS_PAD 65664

typedef short short8 __attribute__((ext_vector_type(8)));
typedef float floatx4 __attribute__((ext_vector_type(4)));

#if __has_builtin(__builtin_amdgcn_fmed3f)
#define MED3(v, hi, lo) __builtin_amdgcn_fmed3f((v), (hi), (lo))
#else
#define MED3(v, hi, lo) fmaxf(fminf((v), (hi)), (lo))
#endif

__device__ __forceinline__ unsigned short f2bf(float x) {
  unsigned int u = __float_as_uint(x);
  u += 0x7FFFu + ((u >> 16) & 1u);  // round-to-nearest-even
  return (unsigned short)(u >> 16);
}
__device__ __forceinline__ float bf2f(unsigned short h) {
  return __uint_as_float(((unsigned int)h) << 16);
}

// Branchless sorted-descending top-16 insert: 15 med3 + 1 max, depth-1 ILP.
__device__ __forceinline__ void insert16(float (&top)[16], float v) {
#pragma unroll
  for (int j = 15; j >= 1; --j) top[j] = MED3(v, top[j - 1], top[j]);
  top[0] = fmaxf(top[0], v);
}

// ---------------------------------------------------------------------------
// Unified pack: one wave per row, l2-normalize + bf16 hi/lo split.
// wave id: [0,65536) patches; [65536,65600) cls; [65600,65664) zero-pad;
// [65664,66176) text rows -> Bh/Bl. Wave-uniform branches only.
__global__ __launch_bounds__(256) void pack_all_kernel(
    const float* __restrict__ vpat, const float* __restrict__ vcls,
    const float* __restrict__ text, unsigned short* __restrict__ Ahi,
    unsigned short* __restrict__ Alo, unsigned short* __restrict__ Bh,
    unsigned short* __restrict__ Bl) {
  const int wid = blockIdx.x * 4 + (threadIdx.x >> 6);
  const int lane = threadIdx.x & 63;
  const float* src;
  unsigned short *hi, *lo;
  size_t orow;
  if (wid < 65536) {
    src = vpat + (size_t)wid * 512; hi = Ahi; lo = Alo; orow = wid;
  } else if (wid < 65600) {
    src = vcls + (size_t)(wid - 65536) * 512; hi = Ahi; lo = Alo; orow = wid;
  } else if (wid < 65664) {
    const ushort4 z = {0, 0, 0, 0};
    ((ushort4*)(Ahi + (size_t)wid * 512))[lane] = z;
    ((ushort4*)(Ahi + (size_t)wid * 512))[lane + 64] = z;
    ((ushort4*)(Alo + (size_t)wid * 512))[lane] = z;
    ((ushort4*)(Alo + (size_t)wid * 512))[lane + 64] = z;
    return;
  } else {
    src = text + (size_t)(wid - 65664) * 512; hi = Bh; lo = Bl;
    orow = wid - 65664;
  }
  const float4 v0 = ((const float4*)src)[lane];
  const float4 v1 = ((const float4*)src)[lane + 64];
  float ss = v0.x * v0.x + v0.y * v0.y + v0.z * v0.z + v0.w * v0.w +
             v1.x * v1.x + v1.y * v1.y + v1.z * v1.z + v1.w * v1.w;
#pragma unroll
  for (int off = 32; off; off >>= 1) ss += __shfl_xor(ss, off);
  const float scale = 1.0f / fmaxf(sqrtf(ss), 1e-12f);
  float a[8] = {v0.x * scale, v0.y * scale, v0.z * scale, v0.w * scale,
                v1.x * scale, v1.y * scale, v1.z * scale, v1.w * scale};
  ushort4 h0, l0, h1, l1;
  h0.x = f2bf(a[0]); l0.x = f2bf(a[0] - bf2f(h0.x));
  h0.y = f2bf(a[1]); l0.y = f2bf(a[1] - bf2f(h0.y));
  h0.z = f2bf(a[2]); l0.z = f2bf(a[2] - bf2f(h0.z));
  h0.w = f2bf(a[3]); l0.w = f2bf(a[3] - bf2f(h0.w));
  h1.x = f2bf(a[4]); l1.x = f2bf(a[4] - bf2f(h1.x));
  h1.y = f2bf(a[5]); l1.y = f2bf(a[5] - bf2f(h1.y));
  h1.z = f2bf(a[6]); l1.z = f2bf(a[6] - bf2f(h1.z));
  h1.w = f2bf(a[7]); l1.w = f2bf(a[7] - bf2f(h1.w));
  ((ushort4*)(hi + orow * 512))[lane] = h0;
  ((ushort4*)(hi + orow * 512))[lane + 64] = h1;
  ((ushort4*)(lo + orow * 512))[lane] = l0;
  ((ushort4*)(lo + orow * 512))[lane + 64] = l1;
}

// ---------------------------------------------------------------------------
// Split-bf16 3-term MFMA GEMM + slim fused softmax partial sum.
// logits[m][c] = A[m][:] . B[c][:], K=512. Block 256 thr (2x2 waves),
// tile 128x128, BK=32, 16x16x32 bf16 MFMA, XOR-swizzled 16B-chunk LDS.
// |logit| <= 1 (l2-normalized rows) -> fixed softmax max 1.0, no max-reduce.
// XCD-aware remap: linear grid 2052; the 4 bn-blocks sharing an A tile are
// mapped to the SAME XCD (assuming round-robin linear%8 assignment) and
// adjacent slots -> A tile fetched into that XCD's L2 once, 3 L2 hits.
__global__ __launch_bounds__(256) void gemm_split_kernel(
    const unsigned short* __restrict__ Ahi, const unsigned short* __restrict__ Alo,
    const unsigned short* __restrict__ Bhi, const unsigned short* __restrict__ Blo,
    float* __restrict__ Cout, float* __restrict__ pstat) {
  __shared__ unsigned short sAh[128 * 32], sAl[128 * 32], sBh[128 * 32], sBl[128 * 32];
  const int tid = threadIdx.x;
  const int lane = tid & 63;
  const int w = tid >> 6;
  const int wm = w >> 1, wn = w & 1;

  // XCD-aware decode of (bm, bn) from linear block id.
  const int L = blockIdx.x;  // 0..2051
  int bm, bn;
  if (L < 2048) {
    const int xcd = L & 7;
    const int slot = L >> 3;   // 0..255 within XCD
    bn = slot & 3;
    bm = (slot >> 2) * 8 + xcd;  // 0..511
  } else {
    bm = 512;
    bn = L - 2048;
  }

  const int i0 = tid, i1 = 256 + tid;
  const int m0 = i0 >> 2, g0 = (i0 & 3) ^ ((m0 >> 1) & 3);
  const int m1 = i1 >> 2, g1 = (i1 & 3) ^ ((m1 >> 1) & 3);
  const unsigned aO0 = (unsigned)(bm * 128 + m0) * 512u + (unsigned)g0 * 8u;
  const unsigned aO1 = (unsigned)(bm * 128 + m1) * 512u + (unsigned)g1 * 8u;
  const unsigned bO0 = (unsigned)(bn * 128 + m0) * 512u + (unsigned)g0 * 8u;
  const unsigned bO1 = (unsigned)(bn * 128 + m1) * 512u + (unsigned)g1 * 8u;
  const unsigned ldsQ0 = (unsigned)(w * 64) * 8u;
  const unsigned ldsQ1 = (unsigned)(256 + w * 64) * 8u;

  const int l15 = lane & 15, kg = lane >> 4;
  int cA[4], cB[4];
#pragma unroll
  for (int i = 0; i < 4; ++i) {
    const int ml = wm * 64 + i * 16 + l15;
    cA[i] = (ml * 4 + (kg ^ ((ml >> 1) & 3))) * 8;
    const int nl = wn * 64 + i * 16 + l15;
    cB[i] = (nl * 4 + (kg ^ ((nl >> 1) & 3))) * 8;
  }

  floatx4 acc[4][4] = {};

#define GL16(srcp, dstp)                                                        \
  __builtin_amdgcn_global_load_lds(                                             \
      (const __attribute__((address_space(1))) void*)(srcp),                    \
      (__attribute__((address_space(3))) void*)(dstp), 16, 0, 0)

  for (int ks = 0; ks < 16; ++ks) {
    const unsigned ko = (unsigned)ks * 32u;
    GL16(Ahi + aO0 + ko, sAh + ldsQ0);
    GL16(Ahi + aO1 + ko, sAh + ldsQ1);
    GL16(Alo + aO0 + ko, sAl + ldsQ0);
    GL16(Alo + aO1 + ko, sAl + ldsQ1);
    GL16(Bhi + bO0 + ko, sBh + ldsQ0);
    GL16(Bhi + bO1 + ko, sBh + ldsQ1);
    GL16(Blo + bO0 + ko, sBl + ldsQ0);
    GL16(Blo + bO1 + ko, sBl + ldsQ1);
    __syncthreads();

    short8 ah[4], al[4], bh[4], bl[4];
#pragma unroll
    for (int i = 0; i < 4; ++i) {
      ah[i] = *(const short8*)(sAh + cA[i]);
      al[i] = *(const short8*)(sAl + cA[i]);
      bh[i] = *(const short8*)(sBh + cB[i]);
      bl[i] = *(const short8*)(sBl + cB[i]);
    }
#pragma unroll
    for (int i = 0; i < 4; ++i) {
#pragma unroll
      for (int j = 0; j < 4; ++j) {
        acc[i][j] = __builtin_amdgcn_mfma_f32_16x16x32_bf16(ah[i], bh[j], acc[i][j], 0, 0, 0);
        acc[i][j] = __builtin_amdgcn_mfma_f32_16x16x32_bf16(ah[i], bl[j], acc[i][j], 0, 0, 0);
        acc[i][j] = __builtin_amdgcn_mfma_f32_16x16x32_bf16(al[i], bh[j], acc[i][j], 0, 0, 0);
      }
    }
    __syncthreads();
  }
#undef GL16

  // C/D layout: col=lane&15, row=(lane>>4)*4+reg  [m89/m91 verified]
  const int quad = lane >> 4;
  const unsigned rowb0 = (unsigned)(bm * 128 + wm * 64 + quad * 4);
  const unsigned colb0 = (unsigned)(bn * 128 + wn * 64 + l15);
#pragma unroll
  for (int i = 0; i < 4; ++i) {
#pragma unroll
    for (int j = 0; j < 4; ++j) {
      const unsigned col = colb0 + j * 16;
#pragma unroll
      for (int r = 0; r < 4; ++r) {
        const unsigned row = rowb0 + i * 16 + r;
        Cout[(size_t)row * 512 + col] = acc[i][j][r];
      }
    }
  }

  // Slim fused partial sumexp (fixed max=1.0): 16-lane quad shfl-sum only.
  const int pk = bn * 2 + wn;  // slot 0..7
#pragma unroll
  for (int i = 0; i < 4; ++i) {
#pragma unroll
    for (int r = 0; r < 4; ++r) {
      float se = __expf((acc[i][0][r] - 1.0f) * INV_TEMP) +
                 __expf((acc[i][1][r] - 1.0f) * INV_TEMP) +
                 __expf((acc[i][2][r] - 1.0f) * INV_TEMP) +
                 __expf((acc[i][3][r] - 1.0f) * INV_TEMP);
      se += __shfl_xor(se, 1);
      se += __shfl_xor(se, 2);
      se += __shfl_xor(se, 4);
      se += __shfl_xor(se, 8);
      if (l15 == 0) {
        const unsigned row = rowb0 + i * 16 + r;
        pstat[(size_t)row * 8 + pk] = se;
      }
    }
  }
}

// ---------------------------------------------------------------------------
// Partial top-16 per (b,c) over an n-chunk of 256, in s = l*invT + LW[n]
// domain. LW computed per-block from pstat (fixed-max-1.0 log-sum-exp):
// LW[m] = -(ln(sum_k pstat[m][k]) + invT). No separate lw kernel.
__global__ __launch_bounds__(256) void topk_partial_kernel(
    const float* __restrict__ L, const float* __restrict__ pstat,
    float* __restrict__ cand) {
  const int b = blockIdx.x;
  const int c = blockIdx.y * 256 + threadIdx.x;
  const int nc = blockIdx.z;
  const size_t mb = (size_t)b * 1024 + (size_t)nc * 256;

  __shared__ float sLW[256];
  {
    const float* p = pstat + (mb + threadIdx.x) * 8;
    float S = 0.f;
#pragma unroll
    for (int k = 0; k < 8; ++k) S += p[k];
    sLW[threadIdx.x] = -(__logf(S) + INV_TEMP);
  }
  __syncthreads();

  float top[16];
#pragma unroll
  for (int t = 0; t < 16; ++t) top[t] = -3.0e38f;
  const float* Lp = L + mb * 512 + c;
  for (int n0 = 0; n0 < 256; n0 += 8) {
    float s[8];
#pragma unroll
    for (int u = 0; u < 8; ++u)
      s[u] = fmaf(Lp[(size_t)(n0 + u) * 512], INV_TEMP, sLW[n0 + u]);
#pragma unroll
    for (int u = 0; u < 8; ++u) insert16(top, s[u]);
  }
  float* o = cand + ((size_t)b * 4 + nc) * 16 * 512 + c;
#pragma unroll
  for (int t = 0; t < 16; ++t) o[(size_t)t * 512] = top[t];
}

// Merge 4x16 s-candidates -> top-16 mean; fused aff_g from cls logit row
// (its LW computed inline from pstat).
__global__ __launch_bounds__(256) void topk_merge_kernel(
    const float* __restrict__ cand, const float* __restrict__ logits,
    const float* __restrict__ pstat, float* __restrict__ out) {
  const int gid = blockIdx.x * 256 + threadIdx.x;  // b*512 + c
  const int b = gid >> 9, c = gid & 511;
  const float* cb = cand + (size_t)b * 64 * 512 + c;
  float top[16];
#pragma unroll
  for (int t = 0; t < 16; ++t) top[t] = -3.0e38f;
#pragma unroll
  for (int kb = 0; kb < 4; ++kb) {
    float v[16];
#pragma unroll
    for (int j = 0; j < 16; ++j) v[j] = cb[(size_t)(kb * 16 + j) * 512];
#pragma unroll
    for (int j = 0; j < 16; ++j) insert16(top, v[j]);
  }
  float s = 0.f;
#pragma unroll
  for (int t = 0; t < 16; ++t) s += __expf(top[t]);
  // cls affinity: row 65536+b
  const float* pc = pstat + ((size_t)65536 + b) * 8;
  float S = 0.f;
#pragma unroll
  for (int k = 0; k < 8; ++k) S += pc[k];
  const float lg = logits[((size_t)65536 + b) * 512 + c];
  const float ag = __expf(fmaf(lg, INV_TEMP, -(__logf(S) + INV_TEMP)));
  out[gid] = GAMMA_ * ag + (1.0f - GAMMA_) * (s * (1.0f / 16.0f));
}

// ---------------------------------------------------------------------------
extern "C" void kernel_launch(void* const* d_in, const int* in_sizes, int n_in,
                              void* d_out, int out_size, void* d_ws, size_t ws_size,
                              hipStream_t stream) {
  const float* vcls = (const float*)d_in[0];  // [64,512]
  const float* vpat = (const float*)d_in[1];  // [64,1024,512]
  const float* text = (const float*)d_in[2];  // [512,512]
  float* out = (float*)d_out;                 // [64,512]

  char* p = (char*)d_ws;
  auto carve = [&](size_t bytes) -> char* {
    char* r = p;
    p += (bytes + 255) & ~(size_t)255;
    return r;
  };
  unsigned short* Ahi = (unsigned short*)carve((size_t)ROWS_PAD * 512 * 2);
  unsigned short* Alo = (unsigned short*)carve((size_t)ROWS_PAD * 512 * 2);
  float* logits = (float*)carve((size_t)ROWS_PAD * 512 * 4);
  unsigned short* Bh = (unsigned short*)carve((size_t)512 * 512 * 2);
  unsigned short* Bl = (unsigned short*)carve((size_t)512 * 512 * 2);
  float* pstat = (float*)carve((size_t)65792 * 8 * 4);
  // cand [64][4][16][512] f32 = 8.4 MB aliases Ahi (dead after gemm).
  float* cand = (float*)Ahi;
  if ((size_t)(p - (char*)d_ws) > ws_size) return;

  pack_all_kernel<<<16544, 256, 0, stream>>>(vpat, vcls, text, Ahi, Alo, Bh, Bl);
  gemm_split_kernel<<<2052, 256, 0, stream>>>(Ahi, Alo, Bh, Bl, logits, pstat);
  topk_partial_kernel<<<dim3(64, 2, 4), 256, 0, stream>>>(logits, pstat, cand);
  topk_merge_kernel<<<128, 256, 0, stream>>>(cand, logits, pstat, out);
}

// Round 6
// 359.668 us; speedup vs baseline: 1.1323x; 1.0711x over previous
//
#include <hip/hip_runtime.h>
#include <cstdint>
#include <cstddef>

// Problem constants: B=64, N=1024, D=512, C=512, K=16, GAMMA=0.3, TEMP=0.07
#define INV_TEMP 14.285714285714285714f
#define GAMMA_ 0.3f

// A rows: 0..65535 = vpat (b*1024+n); 65536..65599 = cls; 65600..65663 = pad.
#define ROWS_PAD 65664

typedef short short8 __attribute__((ext_vector_type(8)));
typedef float floatx4 __attribute__((ext_vector_type(4)));

#if __has_builtin(__builtin_amdgcn_fmed3f)
#define MED3(v, hi, lo) __builtin_amdgcn_fmed3f((v), (hi), (lo))
#else
#define MED3(v, hi, lo) fmaxf(fminf((v), (hi)), (lo))
#endif

__device__ __forceinline__ unsigned short f2bf(float x) {
  unsigned int u = __float_as_uint(x);
  u += 0x7FFFu + ((u >> 16) & 1u);  // round-to-nearest-even
  return (unsigned short)(u >> 16);
}
__device__ __forceinline__ float bf2f(unsigned short h) {
  return __uint_as_float(((unsigned int)h) << 16);
}

// Branchless sorted-descending top-16 insert: 15 med3 + 1 max, depth-1 ILP.
__device__ __forceinline__ void insert16(float (&top)[16], float v) {
#pragma unroll
  for (int j = 15; j >= 1; --j) top[j] = MED3(v, top[j - 1], top[j]);
  top[0] = fmaxf(top[0], v);
}

// ---------------------------------------------------------------------------
// Prep: wave-per-row. wid<512: text row -> l2norm + RNE bf16 hi/lo (B matrix).
// wid 512..639: Aext row (cls raw fp32 copy for rows 0..63; zeros 64..127).
// A-row norms are NOT precomputed -- the GEMM derives them from its own
// fragment reads (zero extra HBM traffic).
__global__ __launch_bounds__(256) void prep_kernel(
    const float* __restrict__ vcls, const float* __restrict__ text,
    unsigned short* __restrict__ Bh, unsigned short* __restrict__ Bl,
    float* __restrict__ Aext) {
  const int wid = blockIdx.x * 4 + (threadIdx.x >> 6);
  const int lane = threadIdx.x & 63;
  if (wid < 512) {
    const float* src = text + (size_t)wid * 512;
    const float4 v0 = ((const float4*)src)[lane];
    const float4 v1 = ((const float4*)src)[lane + 64];
    float ss = v0.x * v0.x + v0.y * v0.y + v0.z * v0.z + v0.w * v0.w +
               v1.x * v1.x + v1.y * v1.y + v1.z * v1.z + v1.w * v1.w;
#pragma unroll
    for (int off = 32; off; off >>= 1) ss += __shfl_xor(ss, off);
    const float scale = 1.0f / fmaxf(sqrtf(ss), 1e-12f);
    float a[8] = {v0.x * scale, v0.y * scale, v0.z * scale, v0.w * scale,
                  v1.x * scale, v1.y * scale, v1.z * scale, v1.w * scale};
    ushort4 h0, l0, h1, l1;
    h0.x = f2bf(a[0]); l0.x = f2bf(a[0] - bf2f(h0.x));
    h0.y = f2bf(a[1]); l0.y = f2bf(a[1] - bf2f(h0.y));
    h0.z = f2bf(a[2]); l0.z = f2bf(a[2] - bf2f(h0.z));
    h0.w = f2bf(a[3]); l0.w = f2bf(a[3] - bf2f(h0.w));
    h1.x = f2bf(a[4]); l1.x = f2bf(a[4] - bf2f(h1.x));
    h1.y = f2bf(a[5]); l1.y = f2bf(a[5] - bf2f(h1.y));
    h1.z = f2bf(a[6]); l1.z = f2bf(a[6] - bf2f(h1.z));
    h1.w = f2bf(a[7]); l1.w = f2bf(a[7] - bf2f(h1.w));
    ((ushort4*)(Bh + (size_t)wid * 512))[lane] = h0;
    ((ushort4*)(Bh + (size_t)wid * 512))[lane + 64] = h1;
    ((ushort4*)(Bl + (size_t)wid * 512))[lane] = l0;
    ((ushort4*)(Bl + (size_t)wid * 512))[lane + 64] = l1;
  } else {
    const int r = wid - 512;  // 0..127
    float4* dst = (float4*)(Aext + (size_t)r * 512);
    if (r < 64) {
      const float4* src = (const float4*)(vcls + (size_t)r * 512);
      dst[lane] = src[lane];
      dst[lane + 64] = src[lane + 64];
    } else {
      const float4 z = {0.f, 0.f, 0.f, 0.f};
      dst[lane] = z;
      dst[lane + 64] = z;
    }
  }
}

// ---------------------------------------------------------------------------
// Raw-A split-bf16 3-term MFMA GEMM, norms-in-kernel, fused softmax partials.
// logits[m][c] = (rawA[m][:] . Bnorm[c][:]) / ||rawA[m]||, K=512.
// Block 256 thr (2x2 waves), tile 128x128, BK=32, 16x16x32 bf16 MFMA.
// A staged as RAW fp32 via global_load_lds (16B chunks, pos = g ^ (row&7)
// swizzle -> frag ds_read_b128 at uniform 8 lanes/bank-group). fp32->(ah,al)
// bf16 split happens in registers per fragment (round-half-away hi, exact
// residual, truncated lo); ssq accumulated during conversion gives row norms
// via quad shfl-reduce (xor 16,32) -- no pack kernel, no norm kernel.
// |scaled logit| <= 1 -> fixed softmax max 1.0 partial sumexp (as r5).
// XCD remap (verified r5: FETCH 267->83 MB): linear%8 = XCD; the 4 bn-blocks
// of an A tile land on one XCD, adjacent slots.
__global__ __launch_bounds__(256) void gemm_raw_kernel(
    const float* __restrict__ Apat, const float* __restrict__ Aext,
    const unsigned short* __restrict__ Bhi, const unsigned short* __restrict__ Blo,
    float* __restrict__ Cout, float* __restrict__ pstat) {
  __shared__ __align__(16) unsigned char smem[32768];
  float* sA = (float*)smem;                              // 128 x 32 fp32 (16 KB)
  unsigned short* sBh = (unsigned short*)(smem + 16384); // 128 x 32 bf16 (8 KB)
  unsigned short* sBl = (unsigned short*)(smem + 24576); // 8 KB
  const int tid = threadIdx.x;
  const int lane = tid & 63;
  const int w = tid >> 6;
  const int wm = w >> 1, wn = w & 1;

  const int L = blockIdx.x;  // 0..2051
  int bm, bn;
  if (L < 2048) {
    const int xcd = L & 7;
    const int slot = L >> 3;
    bn = slot & 3;
    bm = (slot >> 2) * 8 + xcd;
  } else {
    bm = 512;
    bn = L - 2048;
  }
  const float* Abase =
      (bm < 512) ? (Apat + (size_t)bm * 128 * 512) : Aext;

  // A staging: 1024 16B-slots; thread owns slots tid + q*256.
  // slot s -> row = s>>3, pos = s&7, source chunk g = pos ^ (row&7).
  unsigned aSrc[4];
#pragma unroll
  for (int q = 0; q < 4; ++q) {
    const int s = tid + q * 256;
    const int row = s >> 3, pos = s & 7;
    const int g = pos ^ (row & 7);
    aSrc[q] = (unsigned)row * 512u + (unsigned)g * 4u;  // float offset
  }
  // B staging: as r5 (4 chunks/row, pos = g ^ ((row>>1)&3)).
  const int m0 = tid >> 2, g0 = (tid & 3) ^ ((m0 >> 1) & 3);
  const int i1 = 256 + tid;
  const int m1 = i1 >> 2, g1 = (i1 & 3) ^ ((m1 >> 1) & 3);
  const unsigned bO0 = (unsigned)(bn * 128 + m0) * 512u + (unsigned)g0 * 8u;
  const unsigned bO1 = (unsigned)(bn * 128 + m1) * 512u + (unsigned)g1 * 8u;

  const int l15 = lane & 15, kg = lane >> 4;
  int fA0[4], fA1[4], cB[4];
#pragma unroll
  for (int i = 0; i < 4; ++i) {
    const int ml = wm * 64 + i * 16 + l15;
    const int p0 = (2 * kg) ^ (ml & 7);
    const int p1 = (2 * kg + 1) ^ (ml & 7);
    fA0[i] = (ml * 8 + p0) * 4;  // float index
    fA1[i] = (ml * 8 + p1) * 4;
    const int nl = wn * 64 + i * 16 + l15;
    cB[i] = (nl * 4 + (kg ^ ((nl >> 1) & 3))) * 8;  // ushort index
  }

  floatx4 acc[4][4] = {};
  float ssq[4] = {0.f, 0.f, 0.f, 0.f};

#define GL16(srcp, dstp)                                                        \
  __builtin_amdgcn_global_load_lds(                                             \
      (const __attribute__((address_space(1))) void*)(srcp),                    \
      (__attribute__((address_space(3))) void*)(dstp), 16, 0, 0)

  for (int ks = 0; ks < 16; ++ks) {
    const unsigned ko = (unsigned)ks * 32u;  // 32 elements (fp32 or bf16)
#pragma unroll
    for (int q = 0; q < 4; ++q)
      GL16(Abase + aSrc[q] + ko, (unsigned short*)sA + (w * 512 + q * 2048));
    GL16(Bhi + bO0 + ko, sBh + (unsigned)tid * 8u);
    GL16(Bhi + bO1 + ko, sBh + 2048u + (unsigned)tid * 8u);
    GL16(Blo + bO0 + ko, sBl + (unsigned)tid * 8u);
    GL16(Blo + bO1 + ko, sBl + 2048u + (unsigned)tid * 8u);
    __syncthreads();

    short8 bh[4], bl[4];
#pragma unroll
    for (int j = 0; j < 4; ++j) {
      bh[j] = *(const short8*)(sBh + cB[j]);
      bl[j] = *(const short8*)(sBl + cB[j]);
    }
#pragma unroll
    for (int i = 0; i < 4; ++i) {
      const float4 x0 = *(const float4*)(sA + fA0[i]);
      const float4 x1 = *(const float4*)(sA + fA1[i]);
      const float xs[8] = {x0.x, x0.y, x0.z, x0.w, x1.x, x1.y, x1.z, x1.w};
      short8 ah, al;
#pragma unroll
      for (int e = 0; e < 8; ++e) {
        const float f = xs[e];
        ssq[i] = fmaf(f, f, ssq[i]);
        const unsigned u = __float_as_uint(f) + 0x8000u;  // round-half-away
        ah[e] = (short)(u >> 16);
        const float hif = __uint_as_float(u & 0xFFFF0000u);
        al[e] = (short)(__float_as_uint(f - hif) >> 16);  // exact resid, trunc
      }
#pragma unroll
      for (int j = 0; j < 4; ++j) {
        acc[i][j] = __builtin_amdgcn_mfma_f32_16x16x32_bf16(ah, bh[j], acc[i][j], 0, 0, 0);
        acc[i][j] = __builtin_amdgcn_mfma_f32_16x16x32_bf16(ah, bl[j], acc[i][j], 0, 0, 0);
        acc[i][j] = __builtin_amdgcn_mfma_f32_16x16x32_bf16(al, bh[j], acc[i][j], 0, 0, 0);
      }
    }
    __syncthreads();
  }
#undef GL16

  // Row inverse norms: ssq[i] covers row (wm*64 + i*16 + l15), k-partial per
  // quad; xor 16/32 sums over the quad (kg) bits -> full-K ssq on every lane.
  float inv[4];
#pragma unroll
  for (int i = 0; i < 4; ++i) {
    float s = ssq[i];
    s += __shfl_xor(s, 16);
    s += __shfl_xor(s, 32);
    inv[i] = 1.0f / fmaxf(sqrtf(s), 1e-12f);
  }

  // C/D layout: col=lane&15, row=(lane>>4)*4+reg  [m89/m91 verified]
  const int quad = kg;
  const unsigned rowb0 = (unsigned)(bm * 128 + wm * 64 + quad * 4);
  const unsigned colb0 = (unsigned)(bn * 128 + wn * 64 + l15);
  const int pk = bn * 2 + wn;  // pstat slot 0..7
#pragma unroll
  for (int i = 0; i < 4; ++i) {
    // invA for acc rows quad*4+r lives in lane (kg'=quad, l15=quad*4+r).
    float iv[4];
#pragma unroll
    for (int r = 0; r < 4; ++r) iv[r] = __shfl(inv[i], quad * 20 + r);
    float sc[4][4];
#pragma unroll
    for (int j = 0; j < 4; ++j)
#pragma unroll
      for (int r = 0; r < 4; ++r) sc[j][r] = acc[i][j][r] * iv[r];
#pragma unroll
    for (int j = 0; j < 4; ++j) {
      const unsigned col = colb0 + j * 16;
#pragma unroll
      for (int r = 0; r < 4; ++r)
        Cout[(size_t)(rowb0 + i * 16 + r) * 512 + col] = sc[j][r];
    }
    // Fused partial sumexp (fixed max 1.0), reduce over l15 bits (cols).
#pragma unroll
    for (int r = 0; r < 4; ++r) {
      float se = __expf((sc[0][r] - 1.0f) * INV_TEMP) +
                 __expf((sc[1][r] - 1.0f) * INV_TEMP) +
                 __expf((sc[2][r] - 1.0f) * INV_TEMP) +
                 __expf((sc[3][r] - 1.0f) * INV_TEMP);
      se += __shfl_xor(se, 1);
      se += __shfl_xor(se, 2);
      se += __shfl_xor(se, 4);
      se += __shfl_xor(se, 8);
      if (l15 == 0) pstat[(size_t)(rowb0 + i * 16 + r) * 8 + pk] = se;
    }
  }
}

// ---------------------------------------------------------------------------
// Partial top-16 per (b,c) over an n-chunk of 256, in s = l*invT + LW[n]
// domain. LW from pstat (fixed-max-1.0): LW[m] = -(ln(sum_k pstat) + invT).
__global__ __launch_bounds__(256) void topk_partial_kernel(
    const float* __restrict__ L, const float* __restrict__ pstat,
    float* __restrict__ cand) {
  const int b = blockIdx.x;
  const int c = blockIdx.y * 256 + threadIdx.x;
  const int nc = blockIdx.z;
  const size_t mb = (size_t)b * 1024 + (size_t)nc * 256;

  __shared__ float sLW[256];
  {
    const float* p = pstat + (mb + threadIdx.x) * 8;
    float S = 0.f;
#pragma unroll
    for (int k = 0; k < 8; ++k) S += p[k];
    sLW[threadIdx.x] = -(__logf(S) + INV_TEMP);
  }
  __syncthreads();

  float top[16];
#pragma unroll
  for (int t = 0; t < 16; ++t) top[t] = -3.0e38f;
  const float* Lp = L + mb * 512 + c;
  for (int n0 = 0; n0 < 256; n0 += 8) {
    float s[8];
#pragma unroll
    for (int u = 0; u < 8; ++u)
      s[u] = fmaf(Lp[(size_t)(n0 + u) * 512], INV_TEMP, sLW[n0 + u]);
#pragma unroll
    for (int u = 0; u < 8; ++u) insert16(top, s[u]);
  }
  float* o = cand + ((size_t)b * 4 + nc) * 16 * 512 + c;
#pragma unroll
  for (int t = 0; t < 16; ++t) o[(size_t)t * 512] = top[t];
}

// Merge 4x16 s-candidates -> top-16 mean; fused aff_g from cls logit row.
__global__ __launch_bounds__(256) void topk_merge_kernel(
    const float* __restrict__ cand, const float* __restrict__ logits,
    const float* __restrict__ pstat, float* __restrict__ out) {
  const int gid = blockIdx.x * 256 + threadIdx.x;  // b*512 + c
  const int b = gid >> 9, c = gid & 511;
  const float* cb = cand + (size_t)b * 64 * 512 + c;
  float top[16];
#pragma unroll
  for (int t = 0; t < 16; ++t) top[t] = -3.0e38f;
#pragma unroll
  for (int kb = 0; kb < 4; ++kb) {
    float v[16];
#pragma unroll
    for (int j = 0; j < 16; ++j) v[j] = cb[(size_t)(kb * 16 + j) * 512];
#pragma unroll
    for (int j = 0; j < 16; ++j) insert16(top, v[j]);
  }
  float s = 0.f;
#pragma unroll
  for (int t = 0; t < 16; ++t) s += __expf(top[t]);
  const float* pc = pstat + ((size_t)65536 + b) * 8;
  float S = 0.f;
#pragma unroll
  for (int k = 0; k < 8; ++k) S += pc[k];
  const float lg = logits[((size_t)65536 + b) * 512 + c];
  const float ag = __expf(fmaf(lg, INV_TEMP, -(__logf(S) + INV_TEMP)));
  out[gid] = GAMMA_ * ag + (1.0f - GAMMA_) * (s * (1.0f / 16.0f));
}

// ---------------------------------------------------------------------------
extern "C" void kernel_launch(void* const* d_in, const int* in_sizes, int n_in,
                              void* d_out, int out_size, void* d_ws, size_t ws_size,
                              hipStream_t stream) {
  const float* vcls = (const float*)d_in[0];  // [64,512]
  const float* vpat = (const float*)d_in[1];  // [64,1024,512]
  const float* text = (const float*)d_in[2];  // [512,512]
  float* out = (float*)d_out;                 // [64,512]

  char* p = (char*)d_ws;
  auto carve = [&](size_t bytes) -> char* {
    char* r = p;
    p += (bytes + 255) & ~(size_t)255;
    return r;
  };
  float* logits = (float*)carve((size_t)ROWS_PAD * 512 * 4);
  unsigned short* Bh = (unsigned short*)carve((size_t)512 * 512 * 2);
  unsigned short* Bl = (unsigned short*)carve((size_t)512 * 512 * 2);
  float* pstat = (float*)carve((size_t)ROWS_PAD * 8 * 4);
  float* Aext = (float*)carve((size_t)128 * 512 * 4);
  float* cand = (float*)carve((size_t)64 * 4 * 16 * 512 * 4);
  if ((size_t)(p - (char*)d_ws) > ws_size) return;

  prep_kernel<<<160, 256, 0, stream>>>(vcls, text, Bh, Bl, Aext);
  gemm_raw_kernel<<<2052, 256, 0, stream>>>(vpat, Aext, Bh, Bl, logits, pstat);
  topk_partial_kernel<<<dim3(64, 2, 4), 256, 0, stream>>>(logits, pstat, cand);
  topk_merge_kernel<<<128, 256, 0, stream>>>(cand, logits, pstat, out);
}